// Round 8
// baseline (410.664 us; speedup 1.0000x reference)
//
#include <hip/hip_runtime.h>

typedef unsigned short u16;
typedef unsigned int u32;

// workspace offsets (in floats)
#define STATSP 2048     // 16*12*64*2 floats of stats partials
#define KKOFF0 591872
#define KKOFF1 616448
#define KKOFF2 665600
#define WOFF 763904
#define R0OFF 5482496
#define R1OFF 6072320
#define R2OFF 7251968
#define HTOTOFF 11675648
// total = 11712512 floats = ~46.9 MB
// fp64 chain scratch lives INSIDE the Wtil region [WOFF, R0OFF); consumed
// before k_s3 overwrites Wtil. Offsets in doubles rel. to (double*)(ws+WOFF):
#define AD64 0        // 3*65536 doubles  (Ad fp64, per scale)
#define PD64 196608   // 6*65536 doubles  (P ping-pong, per scale)
#define KKD64 589824  // 672*256 doubles  (KK rows: s0 96, s1 192, s2 384)

// ---- k_pre: convert A->fp64, seed KK row0 (fp64+fp32), stats1, zero Htot ----
__global__ __launch_bounds__(256) void k_pre(const float* __restrict__ Ab,
                                             const float* __restrict__ Bb,
                                             const float* __restrict__ xin,
                                             float* __restrict__ ws) {
  __shared__ float rs[4][64], rq[4][64];
  int blk = blockIdx.x, tid = threadIdx.x;
  if (blk < 771) {
    double* dws = (double*)(ws + WOFF);
    int idx = blk * 256 + tid;
    if (idx < 196608) {
      dws[AD64 + idx] = (double)Ab[idx];
    } else {
      int g = idx - 196608;  // 0..767
      const int rowoff[3] = {0, 24576, 73728};
      const int kko[3] = {KKOFF0, KKOFF1, KKOFF2};
      int s = g >> 8, i = g & 255;
      float v = Bb[g];
      dws[KKD64 + rowoff[s] + i] = (double)v;
      ws[kko[s] + i] = v;
    }
  } else if (blk < 963) {
    int b2 = blk - 771;
    int b = b2 / 12, part = b2 % 12;
    int j = tid & 63, g = tid >> 6;
    const float* xp = xin + ((size_t)b * 720 + part * 60 + g) * 64 + j;
    float sum = 0.f, ss = 0.f;
#pragma unroll
    for (int i = 0; i < 15; ++i) {
      float v = xp[(size_t)i * 256];
      sum += v; ss += v * v;
    }
    rs[g][j] = sum; rq[g][j] = ss;
    __syncthreads();
    if (g == 0) {
      float s = rs[0][j] + rs[1][j] + rs[2][j] + rs[3][j];
      float q = rq[0][j] + rq[1][j] + rq[2][j] + rq[3][j];
      float* dst = ws + STATSP + ((size_t)b2 * 64 + j) * 2;
      dst[0] = s; dst[1] = q;
    }
  } else {
    int idx = (blk - 963) * 256 + tid;
    for (; idx < 36864; idx += 24 * 256) ws[HTOTOFF + idx] = 0.f;
  }
}

// ---- fp64 chain GEMM: 16x16 tiles, 64-thread blocks, 2x2 micro, K=N=256 ----
// 1-wave blocks maximize tile parallelism (squaring = 256 tiles full-chip);
// per k-step: 2x ds_read_b128 + 4 fp64 FMA. Register prefetch of next chunk.
struct ChainJobs {
  const double* A[6]; const double* B[6]; double* C[6]; float* CF[6];
  int M[6]; int transB[6]; int tile0[6];
  int njobs;
};

__global__ __launch_bounds__(64) void k_chain16(ChainJobs jb) {
  int bid = blockIdx.x;
  int j = 0;
  for (int q = 1; q < jb.njobs; ++q) if (bid >= jb.tile0[q]) j = q;
  int local = bid - jb.tile0[j];
  int tm = local >> 4, tn = local & 15;
  const double* A = jb.A[j];
  const double* Bm = jb.B[j];
  double* C = jb.C[j];
  float* CF = jb.CF[j];
  int M = jb.M[j], tB = jb.transB[j];
  int row0 = tm * 16, col0 = tn * 16;
  __shared__ double As[32][17], Bs[32][17];
  int tid = threadIdx.x;
  int ty = tid >> 3, tx = tid & 7;
  int arow = tid >> 2, akg = (tid & 3) << 3;   // A / B^T staging: 16 rows x 4 k-groups
  int bk = tid >> 1, bcg = (tid & 1) << 3;     // B staging (no-trans): 32 k x 2 col-groups
  double va[8], vb[8];
#pragma unroll
  for (int u = 0; u < 8; ++u) {
    va[u] = (row0 + arow < M) ? A[(size_t)(row0 + arow) * 256 + akg + u] : 0.0;
    vb[u] = tB ? Bm[(size_t)(col0 + arow) * 256 + akg + u]
               : Bm[(size_t)bk * 256 + col0 + bcg + u];
  }
  double a00 = 0., a01 = 0., a10 = 0., a11 = 0.;
  for (int kc = 0; kc < 256; kc += 32) {
#pragma unroll
    for (int u = 0; u < 8; ++u) {
      As[akg + u][arow] = va[u];
      if (tB) Bs[akg + u][arow] = vb[u];
      else    Bs[bk][bcg + u] = vb[u];
    }
    __syncthreads();
    if (kc < 224) {
      int kn = kc + 32;
#pragma unroll
      for (int u = 0; u < 8; ++u) {
        va[u] = (row0 + arow < M) ? A[(size_t)(row0 + arow) * 256 + kn + akg + u] : 0.0;
        vb[u] = tB ? Bm[(size_t)(col0 + arow) * 256 + kn + akg + u]
                   : Bm[(size_t)(kn + bk) * 256 + col0 + bcg + u];
      }
    }
#pragma unroll 8
    for (int k = 0; k < 32; ++k) {
      double x0 = As[k][ty * 2], x1 = As[k][ty * 2 + 1];
      double y0 = Bs[k][tx * 2], y1 = Bs[k][tx * 2 + 1];
      a00 = fma(x0, y0, a00); a01 = fma(x0, y1, a01);
      a10 = fma(x1, y0, a10); a11 = fma(x1, y1, a11);
    }
    __syncthreads();
  }
  int r0 = row0 + ty * 2, c0 = col0 + tx * 2;
  if (r0 < M) {
    C[(size_t)r0 * 256 + c0] = a00; C[(size_t)r0 * 256 + c0 + 1] = a01;
    if (CF) { CF[(size_t)r0 * 256 + c0] = (float)a00; CF[(size_t)r0 * 256 + c0 + 1] = (float)a01; }
  }
  if (r0 + 1 < M) {
    C[(size_t)(r0 + 1) * 256 + c0] = a10; C[(size_t)(r0 + 1) * 256 + c0 + 1] = a11;
    if (CF) { CF[(size_t)(r0 + 1) * 256 + c0] = (float)a10; CF[(size_t)(r0 + 1) * 256 + c0 + 1] = (float)a11; }
  }
}

// ---- S3: Wtil[i,x,t] = sum_o w[i,o,x]*E[t,o]  (reg double-buffered staging) ----
__global__ __launch_bounds__(256) void k_s3(const float* __restrict__ wr, const float* __restrict__ wi,
                                            const float* __restrict__ ev, float* __restrict__ ws) {
  int bid = blockIdx.x;
  int s = bid >> 8;
  int rem = bid & 255;
  int p = rem >> 7;
  int rt = rem & 127;
  const float* w = (p ? wi : wr) + (size_t)s * 2097152;  // 256*256*32
  const float* E = ev + s * 24576;                       // 96*256
  float* C = ws + WOFF + (size_t)(s * 2 + p) * 786432 + rt * 64 * 96;
  int i0 = rt * 2;
  __shared__ float Ws[32][68];   // [o][i_local*32+x]
  __shared__ float Es[32][102];  // [o][t]  (stride 102: 2-way staging writes = free)
  int tid = threadIdx.x;
  int ty = tid >> 4, tx = tid & 15;
  // staging geometry
  int g = tid * 8;
  int il = g >> 10;
  int o_w = (g & 1023) >> 5, x_w = g & 31;
  const float* wsrc = w + ((size_t)(i0 + il) * 256 + o_w) * 32 + x_w;
  int t_e0 = tid >> 2, oo_e0 = (tid & 3) << 3;
  const float* esrc0 = E + t_e0 * 256 + oo_e0;
  int idx1 = tid + 256;
  int t_e1 = idx1 >> 2, oo_e1 = (idx1 & 3) << 3;
  const float* esrc1 = E + t_e1 * 256 + oo_e1;
  bool has_e1 = (idx1 < 384);
  float4 wv0, wv1, e0a, e0b, e1a, e1b;
  wv0 = *(const float4*)wsrc; wv1 = *(const float4*)(wsrc + 4);
  e0a = *(const float4*)esrc0; e0b = *(const float4*)(esrc0 + 4);
  if (has_e1) { e1a = *(const float4*)esrc1; e1b = *(const float4*)(esrc1 + 4); }
  float acc[4][6];
#pragma unroll
  for (int u = 0; u < 4; ++u)
#pragma unroll
    for (int v = 0; v < 6; ++v) acc[u][v] = 0.f;
  for (int ko = 0; ko < 256; ko += 32) {
    {
      int dst = il * 32 + x_w;
      *(float4*)&Ws[o_w][dst] = wv0;
      *(float4*)&Ws[o_w][dst + 4] = wv1;
      Es[oo_e0 + 0][t_e0] = e0a.x; Es[oo_e0 + 1][t_e0] = e0a.y;
      Es[oo_e0 + 2][t_e0] = e0a.z; Es[oo_e0 + 3][t_e0] = e0a.w;
      Es[oo_e0 + 4][t_e0] = e0b.x; Es[oo_e0 + 5][t_e0] = e0b.y;
      Es[oo_e0 + 6][t_e0] = e0b.z; Es[oo_e0 + 7][t_e0] = e0b.w;
      if (has_e1) {
        Es[oo_e1 + 0][t_e1] = e1a.x; Es[oo_e1 + 1][t_e1] = e1a.y;
        Es[oo_e1 + 2][t_e1] = e1a.z; Es[oo_e1 + 3][t_e1] = e1a.w;
        Es[oo_e1 + 4][t_e1] = e1b.x; Es[oo_e1 + 5][t_e1] = e1b.y;
        Es[oo_e1 + 6][t_e1] = e1b.z; Es[oo_e1 + 7][t_e1] = e1b.w;
      }
    }
    __syncthreads();
    if (ko < 224) {
      const float* wn = wsrc + (ko + 32) * 32;
      wv0 = *(const float4*)wn; wv1 = *(const float4*)(wn + 4);
      const float* en0 = esrc0 + ko + 32;
      e0a = *(const float4*)en0; e0b = *(const float4*)(en0 + 4);
      if (has_e1) {
        const float* en1 = esrc1 + ko + 32;
        e1a = *(const float4*)en1; e1b = *(const float4*)(en1 + 4);
      }
    }
#pragma unroll 4
    for (int k = 0; k < 32; ++k) {
      float4 a = *(const float4*)&Ws[k][ty * 4];
      float2 b0 = *(const float2*)&Es[k][tx * 6];
      float2 b1 = *(const float2*)&Es[k][tx * 6 + 2];
      float2 b2 = *(const float2*)&Es[k][tx * 6 + 4];
      float aa[4] = {a.x, a.y, a.z, a.w};
      float bb[6] = {b0.x, b0.y, b1.x, b1.y, b2.x, b2.y};
#pragma unroll
      for (int u = 0; u < 4; ++u)
#pragma unroll
        for (int v = 0; v < 6; ++v) acc[u][v] += aa[u] * bb[v];
    }
    __syncthreads();
  }
#pragma unroll
  for (int u = 0; u < 4; ++u) {
    int row = ty * 4 + u;
    float* cp = C + row * 96 + tx * 6;
    cp[0] = acc[u][0]; cp[1] = acc[u][1]; cp[2] = acc[u][2];
    cp[3] = acc[u][3]; cp[4] = acc[u][4]; cp[5] = acc[u][5];
  }
}

// ---- S4: R[d,(x,t)] = sum_i KK[d,i]*Wtil[i,(x,t)]  64x64, reg prefetch ----
__global__ __launch_bounds__(256) void k_s4(float* __restrict__ ws) {
  int bid = blockIdx.x;
  const int cums[6] = {0, 96, 192, 336, 480, 768};
  int jidx = 0;
  for (int q = 1; q < 6; ++q) if (bid >= cums[q]) jidx = q;
  int local = bid - cums[jidx];
  int s = jidx >> 1, p = jidx & 1;
  const int Ts[3] = {96, 192, 384};
  const int KKo[3] = {KKOFF0, KKOFF1, KKOFF2};
  const int Ro[3] = {R0OFF, R1OFF, R2OFF};
  int T = Ts[s];
  int tm = local / 48, tn = local % 48;
  int row0 = tm * 64, col0 = tn * 64;
  const float* A = ws + KKo[s];
  const float* B = ws + WOFF + (size_t)(2 * s + p) * 786432;
  float* C = ws + Ro[s] + (size_t)p * T * 3072;
  __shared__ float As[32][68], Bs[32][68];
  int tid = threadIdx.x;
  int ty = tid >> 4, tx = tid & 15;
  int r_a = tid >> 2, k8a = (tid & 3) << 3;
  int k_b = tid >> 3, c8b = (tid & 7) << 3;
  const float* asrc = A + (size_t)(row0 + r_a) * 256 + k8a;
  const float* bsrc = B + (size_t)k_b * 3072 + col0 + c8b;
  bool arow_ok = (row0 + r_a < T);
  float4 av0, av1, bv0, bv1;
  if (arow_ok) { av0 = *(const float4*)asrc; av1 = *(const float4*)(asrc + 4); }
  else { av0 = make_float4(0,0,0,0); av1 = av0; }
  bv0 = *(const float4*)bsrc; bv1 = *(const float4*)(bsrc + 4);
  float acc[4][4];
#pragma unroll
  for (int u = 0; u < 4; ++u)
#pragma unroll
    for (int v = 0; v < 4; ++v) acc[u][v] = 0.f;
  for (int kc = 0; kc < 256; kc += 32) {
    As[k8a + 0][r_a] = av0.x; As[k8a + 1][r_a] = av0.y;
    As[k8a + 2][r_a] = av0.z; As[k8a + 3][r_a] = av0.w;
    As[k8a + 4][r_a] = av1.x; As[k8a + 5][r_a] = av1.y;
    As[k8a + 6][r_a] = av1.z; As[k8a + 7][r_a] = av1.w;
    *(float4*)&Bs[k_b][c8b] = bv0;
    *(float4*)&Bs[k_b][c8b + 4] = bv1;
    __syncthreads();
    if (kc < 224) {
      if (arow_ok) {
        const float* an = asrc + kc + 32;
        av0 = *(const float4*)an; av1 = *(const float4*)(an + 4);
      }
      const float* bn = bsrc + (size_t)(kc + 32) * 3072;
      bv0 = *(const float4*)bn; bv1 = *(const float4*)(bn + 4);
    }
#pragma unroll 8
    for (int k = 0; k < 32; ++k) {
      float4 a = *(const float4*)&As[k][ty * 4];
      float4 b = *(const float4*)&Bs[k][tx * 4];
      float aa[4] = {a.x, a.y, a.z, a.w};
      float bb[4] = {b.x, b.y, b.z, b.w};
#pragma unroll
      for (int u = 0; u < 4; ++u)
#pragma unroll
        for (int v = 0; v < 4; ++v) acc[u][v] += aa[u] * bb[v];
    }
    __syncthreads();
  }
#pragma unroll
  for (int u = 0; u < 4; ++u) {
    int rr = row0 + ty * 4 + u;
    if (rr < T) {
      float* cp = C + (size_t)rr * 3072 + col0 + tx * 4;
      *(float4*)cp = make_float4(acc[u][0], acc[u][1], acc[u][2], acc[u][3]);
    }
  }
}

// ---- S5a: prefix-DFT over d + irfft phase, accumulate w_s * val into Htot ----
__global__ __launch_bounds__(192) void k_s5a(const float* __restrict__ mlpw, float* __restrict__ ws) {
  int bid = blockIdx.x;
  int s = bid >> 7;
  int rem = bid & 127;
  int x = rem >> 2;
  int tq = rem & 3;
  const int Ts[3] = {96, 192, 384};
  const int Ro[3] = {R0OFF, R1OFF, R2OFF};
  const int lpbase[3] = {288, 192, 0};
  int T = Ts[s];
  int Lc = T >> 3;
  __shared__ float cs[384][2];
  __shared__ float Lsr[8][24], Lsi[8][24];
  int tid = threadIdx.x;
  for (int e = tid; e < T; e += 192) {
    float th = 6.283185307179586f * (float)e / (float)T;
    cs[e][0] = cosf(th);
    cs[e][1] = sinf(th);
  }
  int c = tid / 24, tl = tid % 24;
  int t = tq * 24 + tl;
  const float* Rre = ws + Ro[s] + (size_t)x * 96 + t;
  const float* Rim = Rre + (size_t)T * 3072;
  float* Htot = ws + HTOTOFF;
  float wsc = mlpw[s];
  __syncthreads();
  int d0 = c * Lc;
  float zr = 0.f, zi = 0.f;
  for (int d = d0; d < d0 + Lc; ++d) {
    float rr = Rre[(size_t)d * 3072];
    float ri = Rim[(size_t)d * 3072];
    int e1 = (x * d) % T;
    float c1 = cs[e1][0], s1 = cs[e1][1];
    zr += c1 * rr + s1 * ri;
    zi += c1 * ri - s1 * rr;
  }
  Lsr[c][tl] = zr; Lsi[c][tl] = zi;
  __syncthreads();
  if (c == 0) {
    float pr = 0.f, pi = 0.f;
#pragma unroll
    for (int cc = 0; cc < 8; ++cc) {
      float lr = Lsr[cc][tl], li = Lsi[cc][tl];
      Lsr[cc][tl] = pr; Lsi[cc][tl] = pi;
      pr += lr; pi += li;
    }
  }
  __syncthreads();
  zr = Lsr[c][tl]; zi = Lsi[c][tl];
  float sc = (((x == 0) ? 1.f : 2.f) / (float)T) * wsc;
  for (int d = d0; d < d0 + Lc; ++d) {
    float rr = Rre[(size_t)d * 3072];
    float ri = Rim[(size_t)d * 3072];
    int e1 = (x * d) % T;
    float c1 = cs[e1][0], s1 = cs[e1][1];
    zr += c1 * rr + s1 * ri;
    zi += c1 * ri - s1 * rr;
    int k = T - 1 - d;
    int e2 = (x * (95 - k)) % T;
    if (e2 < 0) e2 += T;
    float c2 = cs[e2][0], s2 = cs[e2][1];
    atomicAdd(Htot + (size_t)(lpbase[s] + k) * 96 + t, sc * (c2 * zr - s2 * zi));
  }
}

// ---- S6: out[b,t,j] = sum_l x*Htot + mean*(1-S[t]) + std*mlp_b ----
__global__ __launch_bounds__(256) void k_s6(const float* __restrict__ xin, const float* __restrict__ mlpb_p,
                                            const float* __restrict__ ws, float* __restrict__ out) {
  int b = blockIdx.x >> 2, tq = blockIdx.x & 3;
  int tid = threadIdx.x;
  int j = tid & 63, tsub = tid >> 6;
  __shared__ float Ht[384 * 24];
  for (int idx = tid; idx < 384 * 24; idx += 256) {
    int lp = idx / 24, c = idx % 24;
    Ht[idx] = ws[HTOTOFF + lp * 96 + tq * 24 + c];
  }
  float ssum = 0.f, sq = 0.f;
#pragma unroll
  for (int p = 0; p < 12; ++p) {
    const float* src = ws + STATSP + (((size_t)b * 12 + p) * 64 + j) * 2;
    ssum += src[0]; sq += src[1];
  }
  float mn = ssum * (1.f / 720.f);
  float var = sq * (1.f / 720.f) - mn * mn;
  float sd = sqrtf(var + 1e-5f);
  __syncthreads();
  float mlpb = mlpb_p[0];
  float acc[6] = {0.f, 0.f, 0.f, 0.f, 0.f, 0.f};
  float accS[6] = {0.f, 0.f, 0.f, 0.f, 0.f, 0.f};
  const float* xp = xin + ((size_t)b * 720 + 336) * 64 + j;
  for (int lp = 0; lp < 384; ++lp) {
    float xv = xp[(size_t)lp * 64];
    const float* hr = &Ht[lp * 24 + tsub * 6];
    float2 h01 = *(const float2*)&hr[0];
    float2 h23 = *(const float2*)&hr[2];
    float2 h45 = *(const float2*)&hr[4];
    float hh[6] = {h01.x, h01.y, h23.x, h23.y, h45.x, h45.y};
#pragma unroll
    for (int u = 0; u < 6; ++u) {
      acc[u] += xv * hh[u];
      accS[u] += hh[u];
    }
  }
#pragma unroll
  for (int u = 0; u < 6; ++u) {
    int t = tq * 24 + tsub * 6 + u;
    float val = acc[u] + mn * (1.f - accS[u]) + sd * mlpb;
    out[((size_t)b * 96 + t) * 64 + j] = val;
  }
}

extern "C" void kernel_launch(void* const* d_in, const int* in_sizes, int n_in,
                              void* d_out, int out_size, void* d_ws, size_t ws_size,
                              hipStream_t stream) {
  const float* x  = (const float*)d_in[0];
  const float* wr = (const float*)d_in[1];
  const float* wi = (const float*)d_in[2];
  const float* mw = (const float*)d_in[3];
  const float* mb = (const float*)d_in[4];
  const float* Ab = (const float*)d_in[5];
  const float* Bb = (const float*)d_in[6];
  const float* ev = (const float*)d_in[7];
  float* wsf = (float*)d_ws;
  float* out = (float*)d_out;

  k_pre<<<987, 256, 0, stream>>>(Ab, Bb, x, wsf);

  const double* AD = (const double*)(wsf + WOFF) + AD64;
  double* PD = (double*)(wsf + WOFF) + PD64;
  double* KD = (double*)(wsf + WOFF) + KKD64;
  static const int Ts[3] = {96, 192, 384};
  static const int caps[3] = {32, 64, 128};  // max power needed per scale
  static const int rowoff[3] = {0, 24576, 73728};
  static const int KKo[3] = {KKOFF0, KKOFF1, KKOFF2};

  // Chain: round r extends KK rows [have, have+new) = KK[have-p, have-p+new) * P_p^T
  // with p = min(have, cap); squares P only while next power <= cap.
  int have[3] = {1, 1, 1};
  const double* pptr[3] = {AD, AD + 65536, AD + 131072};
  int pb[3] = {0, 0, 0};
  for (int r = 0; r <= 8; ++r) {
    ChainJobs jb;
    jb.njobs = 0;
    int tiles = 0;
    for (int s = 0; s < 3; ++s) {
      int T = Ts[s];
      if (have[s] >= T) continue;
      int pwr = (have[s] <= caps[s]) ? have[s] : caps[s];
      int nw = (pwr < T - have[s]) ? pwr : (T - have[s]);
      int q = jb.njobs++;
      jb.A[q] = KD + rowoff[s] + (size_t)(have[s] - pwr) * 256;
      jb.B[q] = pptr[s];
      jb.C[q] = KD + rowoff[s] + (size_t)have[s] * 256;
      jb.CF[q] = wsf + KKo[s] + (size_t)have[s] * 256;
      jb.M[q] = nw; jb.transB[q] = 1; jb.tile0[q] = tiles;
      tiles += ((nw + 15) / 16) * 16;
      have[s] += nw;
    }
    for (int s = 0; s < 3; ++s) {
      if ((1 << (r + 1)) <= caps[s]) {
        int q = jb.njobs++;
        double* dst = PD + (size_t)(2 * s + pb[s]) * 65536;
        jb.A[q] = pptr[s]; jb.B[q] = pptr[s];
        jb.C[q] = dst; jb.CF[q] = nullptr;
        jb.M[q] = 256; jb.transB[q] = 0; jb.tile0[q] = tiles;
        tiles += 256;
        pptr[s] = dst; pb[s] ^= 1;
      }
    }
    if (jb.njobs) k_chain16<<<tiles, 64, 0, stream>>>(jb);
  }

  k_s3<<<768, 256, 0, stream>>>(wr, wi, ev, wsf);
  k_s4<<<1056, 256, 0, stream>>>(wsf);
  k_s5a<<<384, 192, 0, stream>>>(mw, wsf);
  k_s6<<<64, 256, 0, stream>>>(x, mb, wsf, out);
}